// Round 4
// baseline (583.811 us; speedup 1.0000x reference)
//
#include <hip/hip_runtime.h>

typedef unsigned short u16;
typedef __attribute__((ext_vector_type(8))) short short8;   // 8 x bf16 (4 VGPRs)
typedef __attribute__((ext_vector_type(4))) float f32x4;    // MFMA C/D frag

#define DEVI __device__ __forceinline__

DEVI float u2f(u16 u) {
    unsigned int x = ((unsigned int)u) << 16;
    float f; __builtin_memcpy(&f, &x, 4); return f;
}
DEVI u16 f2u(float f) {  // RNE bf16 (finite values)
    unsigned int x; __builtin_memcpy(&x, &f, 4);
    x = (x + 0x7fffu + ((x >> 16) & 1u)) >> 16;
    return (u16)x;
}
// async global->LDS, 16B per lane; lds base must be wave-uniform (m104/m108)
DEVI void gld16(const u16* g, u16* ldsbase) {
    __builtin_amdgcn_global_load_lds(
        (const __attribute__((address_space(1))) unsigned int*)g,
        (__attribute__((address_space(3))) unsigned int*)ldsbase, 16, 0, 0);
}

// ---------------------------------------------------------------------------
// Weight transpose: WT[n][k] = bf16(W[k][n]).  W is [K][N] fp32.
// grid: (N/64, K/64), block 256.
__global__ __launch_bounds__(256) void transpose_k(
    const float* __restrict__ W, u16* __restrict__ WT, int K, int N)
{
    __shared__ u16 T[64 * 72];
    const int tid = threadIdx.x;
    const int k0 = blockIdx.y * 64, n0 = blockIdx.x * 64;
#pragma unroll
    for (int i = 0; i < 2; ++i) {
        int c = tid + i * 256;              // 0..511
        int row = c >> 3, n8 = (c & 7) * 8; // row: k-local
        const float* src = &W[(size_t)(k0 + row) * N + n0 + n8];
#pragma unroll
        for (int j = 0; j < 8; ++j)
            T[(n8 + j) * 72 + row] = f2u(src[j]);
    }
    __syncthreads();
#pragma unroll
    for (int i = 0; i < 2; ++i) {
        int c = tid + i * 256;
        int n = c >> 3, k8 = (c & 7) * 8;
        *(short8*)&WT[(size_t)(n0 + n) * K + k0 + k8] = *(const short8*)&T[n * 72 + k8];
    }
}

// ---------------------------------------------------------------------------
// GEMM: C[M][N] = A[M][K] @ WT[N][K]^T (+ optional fp32 residual).
// m97 structure: unpadded [128][32] LDS tiles, global_load_lds width=16 for
// bf16 operands. A is fp32 (a_f32=1, manual convert-stage) or bf16 (lds DMA).
// C written fp32 if c_f32 else bf16.  grid (N/128, M/128), block 256.
__global__ __launch_bounds__(256) void gemm_lds(
    const void* __restrict__ A, int lda, int a_f32,
    const u16* __restrict__ WT,
    void* __restrict__ C, int ldc, const float* __restrict__ resid, int c_f32,
    int M, int N, int K)
{
    __shared__ u16 As[128 * 32];
    __shared__ u16 Bs[128 * 32];
    const int tid = threadIdx.x;
    const int lane = tid & 63, w = tid >> 6;
    const int wm = w >> 1, wn = w & 1;
    const int l15 = lane & 15, quad = lane >> 4;
    const int r4 = lane >> 2, c4 = (lane & 3) * 8;  // DMA: lane->row/col-8
    const int m0 = blockIdx.y * 128, n0 = blockIdx.x * 128;

    f32x4 acc[4][4] = {};
    for (int k0 = 0; k0 < K; k0 += 32) {
        // B tile: 128x32 bf16 via async DMA (2 calls/wave, 1KB each)
#pragma unroll
        for (int j = 0; j < 2; ++j) {
            int row = w * 32 + j * 16;
            gld16(&WT[(size_t)(n0 + row + r4) * K + k0 + c4], &Bs[row * 32]);
        }
        if (a_f32) {
            const float* Xf = (const float*)A;
#pragma unroll
            for (int i = 0; i < 2; ++i) {
                int c = tid + i * 256;
                int row = c >> 2, k8 = (c & 3) * 8;
                const float* src = &Xf[(size_t)(m0 + row) * lda + k0 + k8];
                short8 v;
#pragma unroll
                for (int jj = 0; jj < 8; ++jj) v[jj] = (short)f2u(src[jj]);
                *(short8*)&As[row * 32 + k8] = v;
            }
        } else {
            const u16* Xb = (const u16*)A;
#pragma unroll
            for (int j = 0; j < 2; ++j) {
                int row = w * 32 + j * 16;
                gld16(&Xb[(size_t)(m0 + row + r4) * lda + k0 + c4], &As[row * 32]);
            }
        }
        __syncthreads();
        short8 a[4], b[4];
#pragma unroll
        for (int mt = 0; mt < 4; ++mt)
            a[mt] = *(const short8*)&As[(wm * 64 + mt * 16 + l15) * 32 + quad * 8];
#pragma unroll
        for (int nt = 0; nt < 4; ++nt)
            b[nt] = *(const short8*)&Bs[(wn * 64 + nt * 16 + l15) * 32 + quad * 8];
#pragma unroll
        for (int mt = 0; mt < 4; ++mt)
#pragma unroll
            for (int nt = 0; nt < 4; ++nt)
                acc[mt][nt] = __builtin_amdgcn_mfma_f32_16x16x32_bf16(a[mt], b[nt], acc[mt][nt], 0, 0, 0);
        __syncthreads();
    }
#pragma unroll
    for (int mt = 0; mt < 4; ++mt) {
#pragma unroll
        for (int r = 0; r < 4; ++r) {
            int row = m0 + wm * 64 + mt * 16 + quad * 4 + r;
#pragma unroll
            for (int nt = 0; nt < 4; ++nt) {
                int col = n0 + wn * 64 + nt * 16 + l15;
                float v = acc[mt][nt][r];
                if (resid) v += resid[(size_t)row * ldc + col];
                if (c_f32) ((float*)C)[(size_t)row * ldc + col] = v;
                else       ((u16*)C)[(size_t)row * ldc + col] = f2u(v);
            }
        }
    }
}

// ---------------------------------------------------------------------------
// RMSNorm over dim_head=128, in-place on qkv buffer [4096][3072] (bf16).
// One wave per (token, head); heads 0..15 = q, 16..19 = k. grid 20480, block 256.
__global__ __launch_bounds__(256) void rmsnorm_qk(
    u16* __restrict__ qkv, const float* __restrict__ qg, const float* __restrict__ kg)
{
    const int tid = threadIdx.x, lane = tid & 63, w = tid >> 6;
    const int g = blockIdx.x * 4 + w;        // 0..81919
    const int token = g / 20, head = g % 20;
    const float* gamma; int off;
    if (head < 16) { off = head * 128; gamma = qg; }
    else           { off = 2048 + (head - 16) * 128; gamma = kg; }
    u16* p = qkv + (size_t)token * 3072 + off + lane * 2;
    float f0 = u2f(p[0]), f1 = u2f(p[1]);
    float ss = f0 * f0 + f1 * f1;
#pragma unroll
    for (int m = 1; m < 64; m <<= 1) ss += __shfl_xor(ss, m);
    float r = rsqrtf(ss * (1.0f / 128.0f) + 1e-8f);
    p[0] = f2u(f0 * r * gamma[lane * 2]);
    p[1] = f2u(f1 * r * gamma[lane * 2 + 1]);
}

// ---------------------------------------------------------------------------
// V transpose: vT[(b*4+kvh)*128 + d][s] = qkv[(b*2048+s)][2560 + kvh*128 + d]
// grid (32, 4, 2), block 256.  (bf16)
__global__ __launch_bounds__(256) void vtrans(
    const u16* __restrict__ qkv, u16* __restrict__ vT)
{
    __shared__ u16 T[128 * 72];
    const int tid = threadIdx.x;
    const int t0 = blockIdx.x * 64;
    const int kvh = blockIdx.y, b = blockIdx.z;
#pragma unroll
    for (int i = 0; i < 4; ++i) {
        int c = tid + i * 256;                // 0..1023
        int tl = c >> 4, d8 = (c & 15) * 8;
        short8 v = *(const short8*)&qkv[(size_t)(b * 2048 + t0 + tl) * 3072 + 2560 + kvh * 128 + d8];
#pragma unroll
        for (int j = 0; j < 8; ++j)
            T[(d8 + j) * 72 + tl] = (u16)v[j];
    }
    __syncthreads();
#pragma unroll
    for (int i = 0; i < 4; ++i) {
        int c = tid + i * 256;
        int d = c >> 3, t8 = (c & 7) * 8;
        *(short8*)&vT[((size_t)(b * 4 + kvh) * 128 + d) * 2048 + t0 + t8] =
            *(const short8*)&T[d * 72 + t8];
    }
}

// ---------------------------------------------------------------------------
// Flash attention, causal, GQA. 64 q-rows per block, 64-kv tiles, DH=128.
// Each wave owns 16 q-rows. O written in-place over the Q slice of qkv.
// LDS union: Qs (dead after fragment load) shares space with Vs+Ps -> 45KB
// -> 3 blocks/CU.  qt launched DESCENDING so long causal blocks start first.
// grid (32, 16, 2) = (qtile, head, batch), block 256.
__global__ __launch_bounds__(256) void attn(
    u16* __restrict__ qkv, const u16* __restrict__ vT)
{
    __shared__ u16 lds[22528];               // 45,056 B
    u16* const Ks = lds;                     // [64][136]
    u16* const Qs = lds + 8704;              // [64][136]  dead after qf load
    u16* const Vs = lds + 8704;              // [128][72]  overlays Qs
    u16* const Ps = lds + 17920;             // [64][72]
    const int tid = threadIdx.x, lane = tid & 63, w = tid >> 6;
    const int l15 = lane & 15, quad = lane >> 4;
    const int qt = 31 - (int)blockIdx.x;     // long blocks first
    const int h = blockIdx.y, b = blockIdx.z;
    const int kvh = h >> 2;
    const int q0 = qt * 64;
    const float scale = 0.08838834764831845f;

#pragma unroll
    for (int i = 0; i < 4; ++i) {
        int c = tid + i * 256;
        int r = c >> 4, d8 = (c & 15) * 8;
        *(short8*)&Qs[r * 136 + d8] =
            *(const short8*)&qkv[(size_t)(b * 2048 + q0 + r) * 3072 + h * 128 + d8];
    }
    __syncthreads();
    short8 qf[4];
#pragma unroll
    for (int ks = 0; ks < 4; ++ks)
        qf[ks] = *(const short8*)&Qs[(w * 16 + l15) * 136 + ks * 32 + quad * 8];
    __syncthreads();   // Qs region about to be reused as Vs

    f32x4 o[8] = {};
    float mrow[4], lrow[4];
#pragma unroll
    for (int r = 0; r < 4; ++r) { mrow[r] = -1e30f; lrow[r] = 0.f; }

    for (int kt = 0; kt <= qt; ++kt) {
        const int kv0 = kt * 64;
#pragma unroll
        for (int i = 0; i < 4; ++i) {
            int c = tid + i * 256;
            int r = c >> 4, d8 = (c & 15) * 8;
            *(short8*)&Ks[r * 136 + d8] =
                *(const short8*)&qkv[(size_t)(b * 2048 + kv0 + r) * 3072 + 2048 + kvh * 128 + d8];
        }
#pragma unroll
        for (int i = 0; i < 4; ++i) {
            int c = tid + i * 256;
            int d = c >> 3, t8 = (c & 7) * 8;
            *(short8*)&Vs[d * 72 + t8] =
                *(const short8*)&vT[((size_t)(b * 4 + kvh) * 128 + d) * 2048 + kv0 + t8];
        }
        __syncthreads();

        // S = Q K^T  (each wave: 16 q-rows x 64 kv-cols)
        f32x4 s[4];
#pragma unroll
        for (int nt = 0; nt < 4; ++nt) {
            f32x4 a = {};
#pragma unroll
            for (int ks = 0; ks < 4; ++ks) {
                short8 bk = *(const short8*)&Ks[(nt * 16 + l15) * 136 + ks * 32 + quad * 8];
                a = __builtin_amdgcn_mfma_f32_16x16x32_bf16(qf[ks], bk, a, 0, 0, 0);
            }
            s[nt] = a;
        }
        const bool diag = (kt == qt);
#pragma unroll
        for (int nt = 0; nt < 4; ++nt) {
            int col = nt * 16 + l15;
#pragma unroll
            for (int r = 0; r < 4; ++r) {
                float v = s[nt][r] * scale;
                if (diag) {
                    int row = w * 16 + quad * 4 + r;
                    if (col > row) v = -1e30f;
                }
                s[nt][r] = v;
            }
        }
        // online softmax
        float alpha[4];
#pragma unroll
        for (int r = 0; r < 4; ++r) {
            float mx = s[0][r];
#pragma unroll
            for (int nt = 1; nt < 4; ++nt) mx = fmaxf(mx, s[nt][r]);
#pragma unroll
            for (int msk = 1; msk < 16; msk <<= 1) mx = fmaxf(mx, __shfl_xor(mx, msk));
            float mn = fmaxf(mrow[r], mx);
            alpha[r] = __expf(mrow[r] - mn);
            mrow[r] = mn;
        }
#pragma unroll
        for (int r = 0; r < 4; ++r) {
            float sum = 0.f;
#pragma unroll
            for (int nt = 0; nt < 4; ++nt) {
                float p = __expf(s[nt][r] - mrow[r]);
                s[nt][r] = p;
                sum += p;
            }
#pragma unroll
            for (int msk = 1; msk < 16; msk <<= 1) sum += __shfl_xor(sum, msk);
            lrow[r] = lrow[r] * alpha[r] + sum;
        }
#pragma unroll
        for (int nt = 0; nt < 4; ++nt)
#pragma unroll
            for (int r = 0; r < 4; ++r)
                Ps[(w * 16 + quad * 4 + r) * 72 + nt * 16 + l15] = f2u(s[nt][r]);
#pragma unroll
        for (int nto = 0; nto < 8; ++nto)
#pragma unroll
            for (int r = 0; r < 4; ++r)
                o[nto][r] *= alpha[r];
        __syncthreads();

        // O += P @ V
        short8 pa[2];
#pragma unroll
        for (int ks = 0; ks < 2; ++ks)
            pa[ks] = *(const short8*)&Ps[(w * 16 + l15) * 72 + ks * 32 + quad * 8];
#pragma unroll
        for (int nto = 0; nto < 8; ++nto) {
#pragma unroll
            for (int ks = 0; ks < 2; ++ks) {
                short8 bv = *(const short8*)&Vs[(nto * 16 + l15) * 72 + ks * 32 + quad * 8];
                o[nto] = __builtin_amdgcn_mfma_f32_16x16x32_bf16(pa[ks], bv, o[nto], 0, 0, 0);
            }
        }
        __syncthreads();
    }
    // write O in-place over the Q slice (row stride 3072)
#pragma unroll
    for (int r = 0; r < 4; ++r) {
        float inv = 1.0f / lrow[r];
        int row = q0 + w * 16 + quad * 4 + r;
#pragma unroll
        for (int nto = 0; nto < 8; ++nto)
            qkv[(size_t)(b * 2048 + row) * 3072 + h * 128 + nto * 16 + l15] =
                f2u(o[nto][r] * inv);
    }
}

// ---------------------------------------------------------------------------
// Workspace layout (peak ~44 MiB, proven):
//   [0,         8388608)  WoT   [2048][2048]   live until final GEMM
//   [8388608,  33554432)  QKV   [4096][3072]   q-slice becomes O in-place
//   [33554432, 37748736)  vT    [8][128][2048] written AFTER WTqkv is dead
//   [33554432, 46137344)  WTqkv [3072][2048]   dead after QKV GEMM
extern "C" void kernel_launch(void* const* d_in, const int* in_sizes, int n_in,
                              void* d_out, int out_size, void* d_ws, size_t ws_size,
                              hipStream_t stream) {
    const float* x  = (const float*)d_in[0];   // [2,2048,2048] fp32
    const float* Wq = (const float*)d_in[1];   // [2048,2048]
    const float* Wk = (const float*)d_in[2];   // [2048,512]
    const float* Wv = (const float*)d_in[3];   // [2048,512]
    const float* Wo = (const float*)d_in[4];   // [2048,2048]
    const float* qg = (const float*)d_in[5];   // [128]
    const float* kg = (const float*)d_in[6];   // [128]

    char* ws = (char*)d_ws;
    u16* WoT   = (u16*)(ws);
    u16* QKV   = (u16*)(ws + 8388608);
    u16* vT    = (u16*)(ws + 33554432);
    u16* WTqkv = (u16*)(ws + 33554432);

    // 1. transpose weights into K-inner bf16 layout
    transpose_k<<<dim3(32, 32), 256, 0, stream>>>(Wo, WoT, 2048, 2048);
    transpose_k<<<dim3(32, 32), 256, 0, stream>>>(Wq, WTqkv, 2048, 2048);
    transpose_k<<<dim3(8, 32), 256, 0, stream>>>(Wk, WTqkv + (size_t)2048 * 2048, 2048, 512);
    transpose_k<<<dim3(8, 32), 256, 0, stream>>>(Wv, WTqkv + (size_t)2560 * 2048, 2048, 512);

    // 2. QKV projection: [4096][2048] @ -> [4096][3072]  (A = x fp32)
    gemm_lds<<<dim3(24, 32), 256, 0, stream>>>(x, 2048, 1, WTqkv, QKV, 3072,
                                               nullptr, 0, 4096, 3072, 2048);

    // 3. RMSNorm on q,k heads; V transpose (WTqkv now dead; vT overlays it)
    rmsnorm_qk<<<dim3(20480), 256, 0, stream>>>(QKV, qg, kg);
    vtrans<<<dim3(32, 4, 2), 256, 0, stream>>>(QKV, vT);

    // 4. causal GQA flash attention, O written in-place into QKV's q-slice
    attn<<<dim3(32, 16, 2), 256, 0, stream>>>(QKV, vT);

    // 5. output projection + residual (A = O bf16 via DMA, C = d_out fp32)
    gemm_lds<<<dim3(16, 32), 256, 0, stream>>>(QKV, 3072, 0, WoT, d_out, 2048,
                                               x, 1, 4096, 2048, 2048);
}

// Round 5
// 388.278 us; speedup vs baseline: 1.5036x; 1.5036x over previous
//
#include <hip/hip_runtime.h>

typedef unsigned short u16;
typedef __attribute__((ext_vector_type(8))) short short8;   // 8 x bf16 (4 VGPRs)
typedef __attribute__((ext_vector_type(4))) float f32x4;    // MFMA C/D frag

#define DEVI __device__ __forceinline__

DEVI float u2f(u16 u) {
    unsigned int x = ((unsigned int)u) << 16;
    float f; __builtin_memcpy(&f, &x, 4); return f;
}
DEVI u16 f2u(float f) {  // RNE bf16 (finite values)
    unsigned int x; __builtin_memcpy(&x, &f, 4);
    x = (x + 0x7fffu + ((x >> 16) & 1u)) >> 16;
    return (u16)x;
}
// async global->LDS, 16B per lane; lds base must be wave-uniform (m104/m108)
DEVI void gld16(const u16* g, u16* ldsbase) {
    __builtin_amdgcn_global_load_lds(
        (const __attribute__((address_space(1))) unsigned int*)g,
        (__attribute__((address_space(3))) unsigned int*)ldsbase, 16, 0, 0);
}

// ---------------------------------------------------------------------------
// Weight transpose: WT[n][k] = bf16(W[k][n]).  W is [K][N] fp32.
// grid: (N/64, K/64), block 256.
__global__ __launch_bounds__(256) void transpose_k(
    const float* __restrict__ W, u16* __restrict__ WT, int K, int N)
{
    __shared__ u16 T[64 * 72];
    const int tid = threadIdx.x;
    const int k0 = blockIdx.y * 64, n0 = blockIdx.x * 64;
#pragma unroll
    for (int i = 0; i < 2; ++i) {
        int c = tid + i * 256;              // 0..511
        int row = c >> 3, n8 = (c & 7) * 8; // row: k-local
        const float* src = &W[(size_t)(k0 + row) * N + n0 + n8];
#pragma unroll
        for (int j = 0; j < 8; ++j)
            T[(n8 + j) * 72 + row] = f2u(src[j]);
    }
    __syncthreads();
#pragma unroll
    for (int i = 0; i < 2; ++i) {
        int c = tid + i * 256;
        int n = c >> 3, k8 = (c & 7) * 8;
        *(short8*)&WT[(size_t)(n0 + n) * K + k0 + k8] = *(const short8*)&T[n * 72 + k8];
    }
}

// ---------------------------------------------------------------------------
// GEMM: C[M][N] = A[M][K] @ WT[N][K]^T (+ optional fp32 residual).
// m97 structure: unpadded [128][32] LDS tiles, global_load_lds width=16 for
// bf16 operands. A is fp32 (a_f32=1, manual convert-stage) or bf16 (lds DMA).
// C written fp32 if c_f32 else bf16.  grid (N/128, M/128), block 256.
__global__ __launch_bounds__(256) void gemm_lds(
    const void* __restrict__ A, int lda, int a_f32,
    const u16* __restrict__ WT,
    void* __restrict__ C, int ldc, const float* __restrict__ resid, int c_f32,
    int M, int N, int K)
{
    __shared__ u16 As[128 * 32];
    __shared__ u16 Bs[128 * 32];
    const int tid = threadIdx.x;
    const int lane = tid & 63, w = tid >> 6;
    const int wm = w >> 1, wn = w & 1;
    const int l15 = lane & 15, quad = lane >> 4;
    const int r4 = lane >> 2, c4 = (lane & 3) * 8;  // DMA: lane->row/col-8
    const int m0 = blockIdx.y * 128, n0 = blockIdx.x * 128;

    f32x4 acc[4][4] = {};
    for (int k0 = 0; k0 < K; k0 += 32) {
        // B tile: 128x32 bf16 via async DMA (2 calls/wave, 1KB each)
#pragma unroll
        for (int j = 0; j < 2; ++j) {
            int row = w * 32 + j * 16;
            gld16(&WT[(size_t)(n0 + row + r4) * K + k0 + c4], &Bs[row * 32]);
        }
        if (a_f32) {
            const float* Xf = (const float*)A;
#pragma unroll
            for (int i = 0; i < 2; ++i) {
                int c = tid + i * 256;
                int row = c >> 2, k8 = (c & 3) * 8;
                const float* src = &Xf[(size_t)(m0 + row) * lda + k0 + k8];
                short8 v;
#pragma unroll
                for (int jj = 0; jj < 8; ++jj) v[jj] = (short)f2u(src[jj]);
                *(short8*)&As[row * 32 + k8] = v;
            }
        } else {
            const u16* Xb = (const u16*)A;
#pragma unroll
            for (int j = 0; j < 2; ++j) {
                int row = w * 32 + j * 16;
                gld16(&Xb[(size_t)(m0 + row + r4) * lda + k0 + c4], &As[row * 32]);
            }
        }
        __syncthreads();
        short8 a[4], b[4];
#pragma unroll
        for (int mt = 0; mt < 4; ++mt)
            a[mt] = *(const short8*)&As[(wm * 64 + mt * 16 + l15) * 32 + quad * 8];
#pragma unroll
        for (int nt = 0; nt < 4; ++nt)
            b[nt] = *(const short8*)&Bs[(wn * 64 + nt * 16 + l15) * 32 + quad * 8];
#pragma unroll
        for (int mt = 0; mt < 4; ++mt)
#pragma unroll
            for (int nt = 0; nt < 4; ++nt)
                acc[mt][nt] = __builtin_amdgcn_mfma_f32_16x16x32_bf16(a[mt], b[nt], acc[mt][nt], 0, 0, 0);
        __syncthreads();
    }
#pragma unroll
    for (int mt = 0; mt < 4; ++mt) {
#pragma unroll
        for (int r = 0; r < 4; ++r) {
            int row = m0 + wm * 64 + mt * 16 + quad * 4 + r;
#pragma unroll
            for (int nt = 0; nt < 4; ++nt) {
                int col = n0 + wn * 64 + nt * 16 + l15;
                float v = acc[mt][nt][r];
                if (resid) v += resid[(size_t)row * ldc + col];
                if (c_f32) ((float*)C)[(size_t)row * ldc + col] = v;
                else       ((u16*)C)[(size_t)row * ldc + col] = f2u(v);
            }
        }
    }
}

// ---------------------------------------------------------------------------
// RMSNorm over dim_head=128, in-place on qkv buffer [4096][3072] (bf16).
// One wave per (token, head); heads 0..15 = q, 16..19 = k. grid 20480, block 256.
__global__ __launch_bounds__(256) void rmsnorm_qk(
    u16* __restrict__ qkv, const float* __restrict__ qg, const float* __restrict__ kg)
{
    const int tid = threadIdx.x, lane = tid & 63, w = tid >> 6;
    const int g = blockIdx.x * 4 + w;        // 0..81919
    const int token = g / 20, head = g % 20;
    const float* gamma; int off;
    if (head < 16) { off = head * 128; gamma = qg; }
    else           { off = 2048 + (head - 16) * 128; gamma = kg; }
    u16* p = qkv + (size_t)token * 3072 + off + lane * 2;
    float f0 = u2f(p[0]), f1 = u2f(p[1]);
    float ss = f0 * f0 + f1 * f1;
#pragma unroll
    for (int m = 1; m < 64; m <<= 1) ss += __shfl_xor(ss, m);
    float r = rsqrtf(ss * (1.0f / 128.0f) + 1e-8f);
    p[0] = f2u(f0 * r * gamma[lane * 2]);
    p[1] = f2u(f1 * r * gamma[lane * 2 + 1]);
}

// ---------------------------------------------------------------------------
// V transpose: vT[(b*4+kvh)*128 + d][s] = qkv[(b*2048+s)][2560 + kvh*128 + d]
// grid (32, 4, 2), block 256.  (bf16)
__global__ __launch_bounds__(256) void vtrans(
    const u16* __restrict__ qkv, u16* __restrict__ vT)
{
    __shared__ u16 T[128 * 72];
    const int tid = threadIdx.x;
    const int t0 = blockIdx.x * 64;
    const int kvh = blockIdx.y, b = blockIdx.z;
#pragma unroll
    for (int i = 0; i < 4; ++i) {
        int c = tid + i * 256;                // 0..1023
        int tl = c >> 4, d8 = (c & 15) * 8;
        short8 v = *(const short8*)&qkv[(size_t)(b * 2048 + t0 + tl) * 3072 + 2560 + kvh * 128 + d8];
#pragma unroll
        for (int j = 0; j < 8; ++j)
            T[(d8 + j) * 72 + tl] = (u16)v[j];
    }
    __syncthreads();
#pragma unroll
    for (int i = 0; i < 4; ++i) {
        int c = tid + i * 256;
        int d = c >> 3, t8 = (c & 7) * 8;
        *(short8*)&vT[((size_t)(b * 4 + kvh) * 128 + d) * 2048 + t0 + t8] =
            *(const short8*)&T[d * 72 + t8];
    }
}

// ---------------------------------------------------------------------------
// Flash attention, causal, GQA, PAIRED q-tiles for perfect load balance:
// block (x,h,b) owns q-tiles qtA = x (0..15) and qtB = 31-x; causal work =
// (qtA+1)+(qtB+1) = 33 kv-tiles for EVERY block -> no stacking imbalance
// (linear-id stride-256 lands on the same CU slot; uniform cost makes that
// harmless).  K/V staged once per kv-tile, shared by both q-tiles.
// Each wave owns 16 q-rows of each tile.  O written in-place over Q slice.
// grid (16, 16, 2), block 256.  LDS 54,272 B -> 2 blocks/CU (matches 2-deep).
__global__ __launch_bounds__(256) void attn(
    u16* __restrict__ qkv, const u16* __restrict__ vT)
{
    __shared__ u16 lds[27136];               // 54,272 B
    u16* const Ks  = lds;                    // [64][136]           8704 elems
    u16* const Vs  = lds + 8704;             // [128][72]           9216 elems
    u16* const Psb[2] = { lds + 17920, lds + 22528 };  // 2x [64][72]
    // Q staging overlays the Vs+Ps region (dead until first kv iteration):
    u16* const Qsb[2] = { lds + 8704, lds + 17408 };   // 2x [64][136]

    const int tid = threadIdx.x, lane = tid & 63, w = tid >> 6;
    const int l15 = lane & 15, quad = lane >> 4;
    const int h = blockIdx.y, b = blockIdx.z;
    const int kvh = h >> 2;
    const int qts[2] = { (int)blockIdx.x, 31 - (int)blockIdx.x };
    const float scale = 0.08838834764831845f;

    // stage both Q tiles, pull fragments to registers
#pragma unroll
    for (int t = 0; t < 2; ++t)
#pragma unroll
        for (int i = 0; i < 4; ++i) {
            int c = tid + i * 256;
            int r = c >> 4, d8 = (c & 15) * 8;
            *(short8*)&Qsb[t][r * 136 + d8] =
                *(const short8*)&qkv[(size_t)(b * 2048 + qts[t] * 64 + r) * 3072 + h * 128 + d8];
        }
    __syncthreads();
    short8 qf[2][4];
#pragma unroll
    for (int t = 0; t < 2; ++t)
#pragma unroll
        for (int ks = 0; ks < 4; ++ks)
            qf[t][ks] = *(const short8*)&Qsb[t][(w * 16 + l15) * 136 + ks * 32 + quad * 8];
    __syncthreads();   // Q region about to be reused as Vs/Ps

    f32x4 o[2][8] = {};
    float mrow[2][4], lrow[2][4];
#pragma unroll
    for (int t = 0; t < 2; ++t)
#pragma unroll
        for (int r = 0; r < 4; ++r) { mrow[t][r] = -1e30f; lrow[t][r] = 0.f; }

    for (int kt = 0; kt <= qts[1]; ++kt) {
        const int kv0 = kt * 64;
#pragma unroll
        for (int i = 0; i < 4; ++i) {
            int c = tid + i * 256;
            int r = c >> 4, d8 = (c & 15) * 8;
            *(short8*)&Ks[r * 136 + d8] =
                *(const short8*)&qkv[(size_t)(b * 2048 + kv0 + r) * 3072 + 2048 + kvh * 128 + d8];
        }
#pragma unroll
        for (int i = 0; i < 4; ++i) {
            int c = tid + i * 256;
            int d = c >> 3, t8 = (c & 7) * 8;
            *(short8*)&Vs[d * 72 + t8] =
                *(const short8*)&vT[((size_t)(b * 4 + kvh) * 128 + d) * 2048 + kv0 + t8];
        }
        __syncthreads();

#pragma unroll
        for (int t = 0; t < 2; ++t) {
            if (kt > qts[t]) continue;       // tile done (wave-uniform branch)
            // S = Q K^T  (16 q-rows x 64 kv-cols)
            f32x4 s[4];
#pragma unroll
            for (int nt = 0; nt < 4; ++nt) {
                f32x4 a = {};
#pragma unroll
                for (int ks = 0; ks < 4; ++ks) {
                    short8 bk = *(const short8*)&Ks[(nt * 16 + l15) * 136 + ks * 32 + quad * 8];
                    a = __builtin_amdgcn_mfma_f32_16x16x32_bf16(qf[t][ks], bk, a, 0, 0, 0);
                }
                s[nt] = a;
            }
            const bool diag = (kt == qts[t]);
#pragma unroll
            for (int nt = 0; nt < 4; ++nt) {
                int col = nt * 16 + l15;
#pragma unroll
                for (int r = 0; r < 4; ++r) {
                    float v = s[nt][r] * scale;
                    if (diag) {
                        int row = w * 16 + quad * 4 + r;
                        if (col > row) v = -1e30f;
                    }
                    s[nt][r] = v;
                }
            }
            // online softmax
            float alpha[4];
#pragma unroll
            for (int r = 0; r < 4; ++r) {
                float mx = s[0][r];
#pragma unroll
                for (int nt = 1; nt < 4; ++nt) mx = fmaxf(mx, s[nt][r]);
#pragma unroll
                for (int msk = 1; msk < 16; msk <<= 1) mx = fmaxf(mx, __shfl_xor(mx, msk));
                float mn = fmaxf(mrow[t][r], mx);
                alpha[r] = __expf(mrow[t][r] - mn);
                mrow[t][r] = mn;
            }
#pragma unroll
            for (int r = 0; r < 4; ++r) {
                float sum = 0.f;
#pragma unroll
                for (int nt = 0; nt < 4; ++nt) {
                    float p = __expf(s[nt][r] - mrow[t][r]);
                    s[nt][r] = p;
                    sum += p;
                }
#pragma unroll
                for (int msk = 1; msk < 16; msk <<= 1) sum += __shfl_xor(sum, msk);
                lrow[t][r] = lrow[t][r] * alpha[r] + sum;
            }
#pragma unroll
            for (int nt = 0; nt < 4; ++nt)
#pragma unroll
                for (int r = 0; r < 4; ++r)
                    Psb[t][(w * 16 + quad * 4 + r) * 72 + nt * 16 + l15] = f2u(s[nt][r]);
#pragma unroll
            for (int nto = 0; nto < 8; ++nto)
#pragma unroll
                for (int r = 0; r < 4; ++r)
                    o[t][nto][r] *= alpha[r];
        }
        __syncthreads();

        // O += P @ V  (per active tile)
#pragma unroll
        for (int t = 0; t < 2; ++t) {
            if (kt > qts[t]) continue;
            short8 pa[2];
#pragma unroll
            for (int ks = 0; ks < 2; ++ks)
                pa[ks] = *(const short8*)&Psb[t][(w * 16 + l15) * 72 + ks * 32 + quad * 8];
#pragma unroll
            for (int nto = 0; nto < 8; ++nto) {
#pragma unroll
                for (int ks = 0; ks < 2; ++ks) {
                    short8 bv = *(const short8*)&Vs[(nto * 16 + l15) * 72 + ks * 32 + quad * 8];
                    o[t][nto] = __builtin_amdgcn_mfma_f32_16x16x32_bf16(pa[ks], bv, o[t][nto], 0, 0, 0);
                }
            }
        }
        __syncthreads();
    }
    // write O in-place over the Q slice (row stride 3072)
#pragma unroll
    for (int t = 0; t < 2; ++t)
#pragma unroll
        for (int r = 0; r < 4; ++r) {
            float inv = 1.0f / lrow[t][r];
            int row = qts[t] * 64 + w * 16 + quad * 4 + r;
#pragma unroll
            for (int nto = 0; nto < 8; ++nto)
                qkv[(size_t)(b * 2048 + row) * 3072 + h * 128 + nto * 16 + l15] =
                    f2u(o[t][nto][r] * inv);
        }
}

// ---------------------------------------------------------------------------
// Workspace layout (peak ~44 MiB, proven):
//   [0,         8388608)  WoT   [2048][2048]   live until final GEMM
//   [8388608,  33554432)  QKV   [4096][3072]   q-slice becomes O in-place
//   [33554432, 37748736)  vT    [8][128][2048] written AFTER WTqkv is dead
//   [33554432, 46137344)  WTqkv [3072][2048]   dead after QKV GEMM
extern "C" void kernel_launch(void* const* d_in, const int* in_sizes, int n_in,
                              void* d_out, int out_size, void* d_ws, size_t ws_size,
                              hipStream_t stream) {
    const float* x  = (const float*)d_in[0];   // [2,2048,2048] fp32
    const float* Wq = (const float*)d_in[1];   // [2048,2048]
    const float* Wk = (const float*)d_in[2];   // [2048,512]
    const float* Wv = (const float*)d_in[3];   // [2048,512]
    const float* Wo = (const float*)d_in[4];   // [2048,2048]
    const float* qg = (const float*)d_in[5];   // [128]
    const float* kg = (const float*)d_in[6];   // [128]

    char* ws = (char*)d_ws;
    u16* WoT   = (u16*)(ws);
    u16* QKV   = (u16*)(ws + 8388608);
    u16* vT    = (u16*)(ws + 33554432);
    u16* WTqkv = (u16*)(ws + 33554432);

    // 1. transpose weights into K-inner bf16 layout
    transpose_k<<<dim3(32, 32), 256, 0, stream>>>(Wo, WoT, 2048, 2048);
    transpose_k<<<dim3(32, 32), 256, 0, stream>>>(Wq, WTqkv, 2048, 2048);
    transpose_k<<<dim3(8, 32), 256, 0, stream>>>(Wk, WTqkv + (size_t)2048 * 2048, 2048, 512);
    transpose_k<<<dim3(8, 32), 256, 0, stream>>>(Wv, WTqkv + (size_t)2560 * 2048, 2048, 512);

    // 2. QKV projection: [4096][2048] @ -> [4096][3072]  (A = x fp32)
    gemm_lds<<<dim3(24, 32), 256, 0, stream>>>(x, 2048, 1, WTqkv, QKV, 3072,
                                               nullptr, 0, 4096, 3072, 2048);

    // 3. RMSNorm on q,k heads; V transpose (WTqkv now dead; vT overlays it)
    rmsnorm_qk<<<dim3(20480), 256, 0, stream>>>(QKV, qg, kg);
    vtrans<<<dim3(32, 4, 2), 256, 0, stream>>>(QKV, vT);

    // 4. causal GQA flash attention (paired q-tiles), O in-place into QKV
    attn<<<dim3(16, 16, 2), 256, 0, stream>>>(QKV, vT);

    // 5. output projection + residual (A = O bf16 via DMA, C = d_out fp32)
    gemm_lds<<<dim3(16, 32), 256, 0, stream>>>(QKV, 3072, 0, WoT, d_out, 2048,
                                               x, 1, 4096, 2048, 2048);
}